// Round 3
// baseline (403.517 us; speedup 1.0000x reference)
//
#include <hip/hip_runtime.h>
#include <hip/hip_bf16.h>

#define T_STEPS 256
#define B_COLS  65536
#define GAMMA_F 0.99f

// Backward affine scan, one thread per column.
//   ret_i = acc * (discount[i+1]*g) + reward[i+1]
//   acc   = is_last[i] ? target_value[i] : ret_i
//   out[i]= (ret_i - value[i])^2 ; out[T-1] = 0
//
// Round-3: force memory-level parallelism.
//  - __launch_bounds__(256, 1): waves-per-eu=1 -> register allocator stops
//    optimizing for occupancy we can't use (grid is fixed at 4 waves/CU).
//  - sched_barrier(0) between the 56-load batch and its consumption: loads
//    cannot be sunk into the compute phase. Consumption in load order gives
//    progressive vmcnt waits.

template <int N>
__device__ __forceinline__ float process_group(
    int i_hi, unsigned b, float acc,
    const float* __restrict__ reward,
    const float* __restrict__ discount,
    const float* __restrict__ value,
    const float* __restrict__ target_value,
    const int*   __restrict__ step_type,
    const int*   __restrict__ rollout_b,
    const int*   __restrict__ train_b,
    float*       __restrict__ out)
{
    float d[N], r[N], tv[N], v[N];
    int   st[N], rb[N], tb[N];

    // Phase 1: issue all 7*N loads back-to-back.
#pragma unroll
    for (int j = 0; j < N; ++j) {
        const unsigned idx  = (unsigned)(i_hi - j) * B_COLS + b;
        const unsigned idx1 = idx + B_COLS;
        d[j]  = discount[idx1];
        r[j]  = reward[idx1];
        tv[j] = target_value[idx];
        v[j]  = value[idx];
        st[j] = step_type[idx];
        rb[j] = rollout_b[idx];
        tb[j] = train_b[idx];
    }

    // Hard scheduling fence: nothing crosses. All loads above stay above.
    __builtin_amdgcn_sched_barrier(0);

    // Phase 2: serial recurrence + stores, consuming in load order.
#pragma unroll
    for (int j = 0; j < N; ++j) {
        const float ret  = fmaf(acc, d[j] * GAMMA_F, r[j]);
        const bool  l    = (st[j] == 2) | (rb[j] != 0) | (tb[j] != 0);
        acc = l ? tv[j] : ret;
        const float diff = ret - v[j];
        out[(unsigned)(i_hi - j) * B_COLS + b] = diff * diff;
    }
    return acc;
}

__global__ __launch_bounds__(256, 1) void td_loss_kernel(
    const float* __restrict__ reward,
    const float* __restrict__ discount,
    const float* __restrict__ value,
    const float* __restrict__ target_value,
    const int*   __restrict__ step_type,
    const int*   __restrict__ rollout_b,
    const int*   __restrict__ train_b,
    float*       __restrict__ out)
{
    const unsigned b = blockIdx.x * blockDim.x + threadIdx.x;

    // last row: init acc, zero output
    const unsigned last = (unsigned)(T_STEPS - 1) * B_COLS + b;
    float acc = target_value[last];
    out[last] = 0.0f;

    // head: i = 254..249 (6 iterations) so the main loop is exact groups of 8
    acc = process_group<6>(T_STEPS - 2, b, acc,
                           reward, discount, value, target_value,
                           step_type, rollout_b, train_b, out);

    // main: i = 248..1 in 31 groups of 8
    for (int i = 248; i >= 8; i -= 8) {
        acc = process_group<8>(i, b, acc,
                               reward, discount, value, target_value,
                               step_type, rollout_b, train_b, out);
    }

    // peeled i = 0: acc unused afterwards, flags irrelevant
    {
        const unsigned idx1 = B_COLS + b;
        const float d   = discount[idx1] * GAMMA_F;
        const float r   = reward[idx1];
        const float ret = fmaf(acc, d, r);
        const float v   = value[b];
        const float diff = ret - v;
        out[b] = diff * diff;
    }
}

extern "C" void kernel_launch(void* const* d_in, const int* in_sizes, int n_in,
                              void* d_out, int out_size, void* d_ws, size_t ws_size,
                              hipStream_t stream) {
    const float* reward       = (const float*)d_in[0];
    const float* discount     = (const float*)d_in[1];
    const float* value        = (const float*)d_in[2];
    const float* target_value = (const float*)d_in[3];
    const int*   step_type    = (const int*)d_in[4];
    const int*   rollout_b    = (const int*)d_in[5];
    const int*   train_b      = (const int*)d_in[6];
    float*       out          = (float*)d_out;

    const int block = 256;
    const int grid  = B_COLS / block;  // 256 blocks, 1 per CU, 4 waves/CU
    td_loss_kernel<<<grid, block, 0, stream>>>(
        reward, discount, value, target_value, step_type, rollout_b, train_b, out);
}